// Round 1
// baseline (569.522 us; speedup 1.0000x reference)
//
#include <hip/hip_runtime.h>

#define HH 1024
#define VV 32000
#define LL 15
#define BB 512

typedef __bf16 bf16x8_t __attribute__((ext_vector_type(8)));
typedef float f32x4_t __attribute__((ext_vector_type(4)));

__device__ __forceinline__ unsigned short f2bf(float f) {
    unsigned int u = __float_as_uint(f);
    unsigned int r = (u + 0x7fffu + ((u >> 16) & 1u)) >> 16;  // RNE
    return (unsigned short)r;
}

// ---------------------------------------------------------------------------
// Attention: per-b block. scores[l] = dot(emb,w1a) + dot(enc[l,b],w1b) + bias
// softmax over L, ctx = sum_l a[l]*enc[l,b,:], write attn weights + cat(emb,ctx)
// ---------------------------------------------------------------------------
__global__ __launch_bounds__(256)
void attn_kernel(const int* __restrict__ ids, const float* __restrict__ enc,
                 const float* __restrict__ embedding,
                 const float* __restrict__ attn1_w, const float* __restrict__ attn1_b,
                 float* __restrict__ attn_out, float* __restrict__ cat_out) {
    const int b = blockIdx.x;
    const int tid = threadIdx.x;
    const int lane = tid & 63, wv = tid >> 6;

    __shared__ float s_scores[LL];
    __shared__ float s_red[4];
    __shared__ float s_embdot;

    const float* embr = embedding + (size_t)ids[b] * HH;

    // dot(emb, w1[:H])
    float p = 0.f;
    for (int j = tid; j < HH; j += 256) p += embr[j] * attn1_w[j];
    #pragma unroll
    for (int o = 32; o; o >>= 1) p += __shfl_down(p, o);
    if (lane == 0) s_red[wv] = p;
    __syncthreads();
    if (tid == 0) s_embdot = s_red[0] + s_red[1] + s_red[2] + s_red[3];
    __syncthreads();
    const float semb = s_embdot + attn1_b[0];

    // per-l scores; wave wv handles l = wv, wv+4, ...
    for (int l = wv; l < LL; l += 4) {
        const float* er = enc + ((size_t)l * BB + b) * HH;
        float q = 0.f;
        for (int j = lane; j < HH; j += 64) q += er[j] * attn1_w[HH + j];
        #pragma unroll
        for (int o = 32; o; o >>= 1) q += __shfl_down(q, o);
        if (lane == 0) s_scores[l] = q + semb;
    }
    __syncthreads();

    // softmax over 15 (redundant per thread)
    float mx = -3.4e38f;
    #pragma unroll
    for (int l = 0; l < LL; l++) mx = fmaxf(mx, s_scores[l]);
    float aw[LL];
    float sum = 0.f;
    #pragma unroll
    for (int l = 0; l < LL; l++) { aw[l] = __expf(s_scores[l] - mx); sum += aw[l]; }
    const float inv = 1.f / sum;
    #pragma unroll
    for (int l = 0; l < LL; l++) aw[l] *= inv;

    if (tid < LL) attn_out[tid * BB + b] = __expf(s_scores[tid] - mx) * inv;

    // ctx + cat write
    for (int j = tid; j < HH; j += 256) {
        float c = 0.f;
        #pragma unroll
        for (int l = 0; l < LL; l++) c += aw[l] * enc[((size_t)l * BB + b) * HH + j];
        cat_out[(size_t)b * (2 * HH) + j] = embr[j];
        cat_out[(size_t)b * (2 * HH) + HH + j] = c;
    }
}

// ---------------------------------------------------------------------------
// NT GEMM: C[M,N] = A[M,K] * B[N,K]^T + bias, optional ReLU.
// 256 threads = 4 waves (2x2), each wave FMxFN frags of 16x16, BK=32.
// f32 global sources converted to bf16 in-reg, staged to LDS.
// mfma_f32_16x16x32_bf16: A row=lane&15, k=(lane>>4)*8+i ; D row=(lane>>4)*4+j, col=lane&15
// ---------------------------------------------------------------------------
template<int FM, int FN, int ACT>
__global__ __launch_bounds__(256)
void gemm_bt(const float* __restrict__ A, const float* __restrict__ B,
             const float* __restrict__ bias, float* __restrict__ C,
             const int K, const int N) {
    constexpr int TM = 32 * FM, TN = 32 * FN;
    __shared__ unsigned short As[TM][32];
    __shared__ unsigned short Bs[TN][32];

    const int tid = threadIdx.x;
    const int lane = tid & 63, wave = tid >> 6;
    const int wm = wave >> 1, wn = wave & 1;
    const int m0 = blockIdx.y * TM, n0 = blockIdx.x * TN;
    const int rlo = lane & 15, khi = lane >> 4;

    f32x4_t acc[FM][FN] = {};

    for (int k0 = 0; k0 < K; k0 += 32) {
        // stage A tile (TM x 32)
        #pragma unroll
        for (int idx = tid; idx < TM * 8; idx += 256) {
            const int r = idx >> 3, c = (idx & 7) << 2;
            const float4 v = *reinterpret_cast<const float4*>(A + (size_t)(m0 + r) * K + k0 + c);
            ushort4 w = make_ushort4(f2bf(v.x), f2bf(v.y), f2bf(v.z), f2bf(v.w));
            *reinterpret_cast<ushort4*>(&As[r][c]) = w;
        }
        // stage B tile (TN x 32)
        #pragma unroll
        for (int idx = tid; idx < TN * 8; idx += 256) {
            const int r = idx >> 3, c = (idx & 7) << 2;
            const float4 v = *reinterpret_cast<const float4*>(B + (size_t)(n0 + r) * K + k0 + c);
            ushort4 w = make_ushort4(f2bf(v.x), f2bf(v.y), f2bf(v.z), f2bf(v.w));
            *reinterpret_cast<ushort4*>(&Bs[r][c]) = w;
        }
        __syncthreads();

        bf16x8_t af[FM], bfr[FN];
        #pragma unroll
        for (int m = 0; m < FM; m++)
            af[m] = *reinterpret_cast<const bf16x8_t*>(&As[wm * 16 * FM + 16 * m + rlo][khi * 8]);
        #pragma unroll
        for (int n = 0; n < FN; n++)
            bfr[n] = *reinterpret_cast<const bf16x8_t*>(&Bs[wn * 16 * FN + 16 * n + rlo][khi * 8]);
        #pragma unroll
        for (int m = 0; m < FM; m++)
            #pragma unroll
            for (int n = 0; n < FN; n++)
                acc[m][n] = __builtin_amdgcn_mfma_f32_16x16x32_bf16(af[m], bfr[n], acc[m][n], 0, 0, 0);
        __syncthreads();
    }

    // epilogue
    #pragma unroll
    for (int m = 0; m < FM; m++)
        #pragma unroll
        for (int n = 0; n < FN; n++)
            #pragma unroll
            for (int j = 0; j < 4; j++) {
                const int gr = m0 + wm * 16 * FM + 16 * m + khi * 4 + j;
                const int gc = n0 + wn * 16 * FN + 16 * n + rlo;
                float v = acc[m][n][j] + bias[gc];
                if (ACT == 1) v = fmaxf(v, 0.f);
                C[(size_t)gr * N + gc] = v;
            }
}

// ---------------------------------------------------------------------------
// GRU elementwise gates
// ---------------------------------------------------------------------------
__global__ __launch_bounds__(256)
void gru_kernel(const float* __restrict__ gi, const float* __restrict__ gh,
                const float* __restrict__ h, float* __restrict__ hnew) {
    const int i = blockIdx.x * 256 + threadIdx.x;  // < BB*HH
    const int b = i >> 10, j = i & (HH - 1);
    const size_t o = (size_t)b * (3 * HH) + j;
    const float ir = gi[o], iz = gi[o + HH], in_ = gi[o + 2 * HH];
    const float hr = gh[o], hz = gh[o + HH], hn = gh[o + 2 * HH];
    const float r = 1.f / (1.f + __expf(-(ir + hr)));
    const float z = 1.f / (1.f + __expf(-(iz + hz)));
    const float n = tanhf(in_ + r * hn);
    hnew[i] = (1.f - z) * n + z * h[i];
}

// ---------------------------------------------------------------------------
// In-place row log-softmax over V=32000
// ---------------------------------------------------------------------------
__global__ __launch_bounds__(256)
void lsm_kernel(float* __restrict__ logits) {
    const int b = blockIdx.x, tid = threadIdx.x;
    float* row = logits + (size_t)b * VV;
    __shared__ float sred[4];

    float mx = -3.4e38f;
    for (int j = tid; j < VV; j += 256) mx = fmaxf(mx, row[j]);
    #pragma unroll
    for (int o = 32; o; o >>= 1) mx = fmaxf(mx, __shfl_down(mx, o));
    if ((tid & 63) == 0) sred[tid >> 6] = mx;
    __syncthreads();
    mx = fmaxf(fmaxf(sred[0], sred[1]), fmaxf(sred[2], sred[3]));
    __syncthreads();

    float s = 0.f;
    for (int j = tid; j < VV; j += 256) s += __expf(row[j] - mx);
    #pragma unroll
    for (int o = 32; o; o >>= 1) s += __shfl_down(s, o);
    if ((tid & 63) == 0) sred[tid >> 6] = s;
    __syncthreads();
    s = sred[0] + sred[1] + sred[2] + sred[3];

    const float lse = mx + logf(s);
    for (int j = tid; j < VV; j += 256) row[j] -= lse;
}

// ---------------------------------------------------------------------------
extern "C" void kernel_launch(void* const* d_in, const int* in_sizes, int n_in,
                              void* d_out, int out_size, void* d_ws, size_t ws_size,
                              hipStream_t stream) {
    const int*   ids       = (const int*)d_in[0];
    const float* hidden    = (const float*)d_in[1];
    const float* enc       = (const float*)d_in[2];
    // d_in[3] = max_length (constant 15)
    const float* embedding = (const float*)d_in[4];
    const float* attn1_w   = (const float*)d_in[5];
    const float* attn1_b   = (const float*)d_in[6];
    const float* combine_w = (const float*)d_in[7];
    const float* combine_b = (const float*)d_in[8];
    const float* w_ih      = (const float*)d_in[9];
    const float* w_hh      = (const float*)d_in[10];
    const float* b_ih      = (const float*)d_in[11];
    const float* b_hh      = (const float*)d_in[12];
    const float* out_w     = (const float*)d_in[13];
    const float* out_b     = (const float*)d_in[14];

    float* out_lsm = (float*)d_out;                       // [B,V]
    float* out_h   = out_lsm + (size_t)BB * VV;           // [1,B,H]
    float* out_aw  = out_h + (size_t)BB * HH;             // [L,B,1]

    float* ws  = (float*)d_ws;
    float* cat = ws;                                      // [B, 2H]
    float* x   = cat + (size_t)BB * 2 * HH;               // [B, H]
    float* gi  = x   + (size_t)BB * HH;                   // [B, 3H]
    float* gh  = gi  + (size_t)BB * 3 * HH;               // [B, 3H]

    attn_kernel<<<BB, 256, 0, stream>>>(ids, enc, embedding, attn1_w, attn1_b, out_aw, cat);

    // x = relu(cat @ combine_w^T + combine_b)   M=512 N=1024 K=2048
    gemm_bt<2, 2, 1><<<dim3(HH / 64, BB / 64), 256, 0, stream>>>(cat, combine_w, combine_b, x, 2 * HH, HH);

    // gh = hidden @ w_hh^T + b_hh               M=512 N=3072 K=1024
    gemm_bt<2, 2, 0><<<dim3(3 * HH / 64, BB / 64), 256, 0, stream>>>(hidden, w_hh, b_hh, gh, HH, 3 * HH);

    // gi = x @ w_ih^T + b_ih                    M=512 N=3072 K=1024
    gemm_bt<2, 2, 0><<<dim3(3 * HH / 64, BB / 64), 256, 0, stream>>>(x, w_ih, b_ih, gi, HH, 3 * HH);

    // h_new
    gru_kernel<<<(BB * HH) / 256, 256, 0, stream>>>(gi, gh, hidden, out_h);

    // logits = h_new @ out_w^T + out_b          M=512 N=32000 K=1024
    gemm_bt<4, 4, 0><<<dim3(VV / 128, BB / 128), 256, 0, stream>>>(out_h, out_w, out_b, out_lsm, HH, VV);

    // in-place log_softmax
    lsm_kernel<<<BB, 256, 0, stream>>>(out_lsm);
}

// Round 2
// 239.672 us; speedup vs baseline: 2.3763x; 2.3763x over previous
//
#include <hip/hip_runtime.h>

#define HH 1024
#define VV 32000
#define LL 15
#define BB 512

typedef __bf16 bf16;
typedef __bf16 bf16x8 __attribute__((ext_vector_type(8)));
typedef float f32x4 __attribute__((ext_vector_type(4)));

__device__ __forceinline__ unsigned short f2bf(float f) {
    unsigned int u = __float_as_uint(f);
    unsigned int r = (u + 0x7fffu + ((u >> 16) & 1u)) >> 16;  // RNE
    return (unsigned short)r;
}

__device__ __forceinline__ void gld_lds16(const void* g, void* l) {
    __builtin_amdgcn_global_load_lds(
        (const __attribute__((address_space(1))) unsigned int*)g,
        (__attribute__((address_space(3))) unsigned int*)l, 16, 0, 0);
}

// ---------------------------------------------------------------------------
// f32 -> bf16 convert, 8 elems/thread
// ---------------------------------------------------------------------------
__global__ __launch_bounds__(256)
void cvt_kernel(const float* __restrict__ in, unsigned short* __restrict__ out, int n8) {
    const int i = blockIdx.x * 256 + threadIdx.x;
    if (i >= n8) return;
    const float4* p = (const float4*)in;
    float4 a = p[2 * i], b = p[2 * i + 1];
    ushort4 lo = make_ushort4(f2bf(a.x), f2bf(a.y), f2bf(a.z), f2bf(a.w));
    ushort4 hi = make_ushort4(f2bf(b.x), f2bf(b.y), f2bf(b.z), f2bf(b.w));
    ushort4* q = (ushort4*)out;
    q[2 * i] = lo; q[2 * i + 1] = hi;
}

// ---------------------------------------------------------------------------
// Attention: per-b block. Writes attn weights (f32) + cat(emb,ctx) as bf16.
// ---------------------------------------------------------------------------
__global__ __launch_bounds__(256)
void attn_kernel(const int* __restrict__ ids, const float* __restrict__ enc,
                 const float* __restrict__ embedding,
                 const float* __restrict__ attn1_w, const float* __restrict__ attn1_b,
                 float* __restrict__ attn_out, unsigned short* __restrict__ cat_out) {
    const int b = blockIdx.x;
    const int tid = threadIdx.x;
    const int lane = tid & 63, wv = tid >> 6;

    __shared__ float s_scores[LL];
    __shared__ float s_red[4];
    __shared__ float s_embdot;

    const float* embr = embedding + (size_t)ids[b] * HH;

    float p = 0.f;
    for (int j = tid; j < HH; j += 256) p += embr[j] * attn1_w[j];
    #pragma unroll
    for (int o = 32; o; o >>= 1) p += __shfl_xor(p, o);
    if (lane == 0) s_red[wv] = p;
    __syncthreads();
    if (tid == 0) s_embdot = s_red[0] + s_red[1] + s_red[2] + s_red[3];
    __syncthreads();
    const float semb = s_embdot + attn1_b[0];

    for (int l = wv; l < LL; l += 4) {
        const float* er = enc + ((size_t)l * BB + b) * HH;
        float q = 0.f;
        for (int j = lane; j < HH; j += 64) q += er[j] * attn1_w[HH + j];
        #pragma unroll
        for (int o = 32; o; o >>= 1) q += __shfl_xor(q, o);
        if (lane == 0) s_scores[l] = q + semb;
    }
    __syncthreads();

    float mx = -3.4e38f;
    #pragma unroll
    for (int l = 0; l < LL; l++) mx = fmaxf(mx, s_scores[l]);
    float aw[LL];
    float sum = 0.f;
    #pragma unroll
    for (int l = 0; l < LL; l++) { aw[l] = __expf(s_scores[l] - mx); sum += aw[l]; }
    const float inv = 1.f / sum;
    #pragma unroll
    for (int l = 0; l < LL; l++) aw[l] *= inv;

    if (tid < LL) attn_out[tid * BB + b] = __expf(s_scores[tid] - mx) * inv;

    for (int j = tid; j < HH; j += 256) {
        float c = 0.f;
        #pragma unroll
        for (int l = 0; l < LL; l++) c += aw[l] * enc[((size_t)l * BB + b) * HH + j];
        cat_out[(size_t)b * (2 * HH) + j] = f2bf(embr[j]);
        cat_out[(size_t)b * (2 * HH) + HH + j] = f2bf(c);
    }
}

// ---------------------------------------------------------------------------
// bf16 NT GEMM (m97 structure): C[M,N] = A[M,K]*B[N,K]^T + bias.
// 256 thr = 4 waves (2x2). BK=64, linear LDS, global_load_lds width=16,
// 2-barrier K-loop. OUT: 0 = f32 store, 1 = relu + bf16 store.
// SWZ: 1D grid; groups of 4 m-blocks sharing a B-panel land on one XCD.
// ---------------------------------------------------------------------------
template<int TM, int TN, int OUT, int SWZ>
__global__ __launch_bounds__(256)
void gemm_nt(const bf16* __restrict__ A, const bf16* __restrict__ B,
             const float* __restrict__ bias, void* __restrict__ Cout,
             const int K, const int N, const int gridN) {
    constexpr int FM = TM / 32, FN = TN / 32;
    __shared__ bf16 As[TM * 64];
    __shared__ bf16 Bs[TN * 64];

    const int tid = threadIdx.x;
    const int lane = tid & 63, wave = tid >> 6;
    const int wm = wave >> 1, wn = wave & 1;
    const int rlo = lane & 15, khi = lane >> 4;

    int m0, n0;
    if (SWZ) {
        // gridDim.x = gridN*4 blocks; member j in [0,4) = m-block, group g = n-block.
        const int b = blockIdx.x;
        const int nFull = (gridN >> 3) << 5;
        int g, j;
        if (b < nFull) { const int s = b >> 5, rem = b & 31; j = rem >> 3; g = s * 8 + (rem & 7); }
        else { const int rem = b - nFull; const int gleft = gridN & 7; g = (gridN & ~7) + rem % gleft; j = rem / gleft; }
        n0 = g * TN; m0 = j * TM;
    } else {
        m0 = blockIdx.y * TM; n0 = blockIdx.x * TN;
    }

    f32x4 acc[FM][FN] = {};
    constexpr int IA = TM / 32, IB = TN / 32;  // global_load_lds issues per thread

    for (int k0 = 0; k0 < K; k0 += 64) {
        #pragma unroll
        for (int i = 0; i < IA; i++) {
            const int t = (i * 256 + tid) * 8;
            gld_lds16(A + (size_t)(m0 + (t >> 6)) * K + (k0 + (t & 63)), As + i * 2048 + wave * 512);
        }
        #pragma unroll
        for (int i = 0; i < IB; i++) {
            const int t = (i * 256 + tid) * 8;
            gld_lds16(B + (size_t)(n0 + (t >> 6)) * K + (k0 + (t & 63)), Bs + i * 2048 + wave * 512);
        }
        __syncthreads();

        bf16x8 af[FM][2], bfr[FN][2];
        #pragma unroll
        for (int m = 0; m < FM; m++)
            #pragma unroll
            for (int ks = 0; ks < 2; ks++)
                af[m][ks] = *(const bf16x8*)(As + (wm * (TM / 2) + m * 16 + rlo) * 64 + ks * 32 + khi * 8);
        #pragma unroll
        for (int n = 0; n < FN; n++)
            #pragma unroll
            for (int ks = 0; ks < 2; ks++)
                bfr[n][ks] = *(const bf16x8*)(Bs + (wn * (TN / 2) + n * 16 + rlo) * 64 + ks * 32 + khi * 8);
        #pragma unroll
        for (int ks = 0; ks < 2; ks++)
            #pragma unroll
            for (int m = 0; m < FM; m++)
                #pragma unroll
                for (int n = 0; n < FN; n++)
                    acc[m][n] = __builtin_amdgcn_mfma_f32_16x16x32_bf16(af[m][ks], bfr[n][ks], acc[m][n], 0, 0, 0);
        __syncthreads();
    }

    #pragma unroll
    for (int m = 0; m < FM; m++) {
        const int gr = m0 + wm * (TM / 2) + m * 16 + khi * 4;
        #pragma unroll
        for (int n = 0; n < FN; n++) {
            const int gc = n0 + wn * (TN / 2) + n * 16 + rlo;
            const float bv = bias[gc];
            #pragma unroll
            for (int j = 0; j < 4; j++) {
                float v = acc[m][n][j] + bv;
                if (OUT == 1) {
                    v = fmaxf(v, 0.f);
                    ((unsigned short*)Cout)[(size_t)(gr + j) * N + gc] = f2bf(v);
                } else {
                    ((float*)Cout)[(size_t)(gr + j) * N + gc] = v;
                }
            }
        }
    }
}

// ---------------------------------------------------------------------------
// GRU gates; writes h_new f32 (output) + bf16 (GEMM A operand)
// ---------------------------------------------------------------------------
__global__ __launch_bounds__(256)
void gru_kernel(const float* __restrict__ gi, const float* __restrict__ gh,
                const float* __restrict__ h, float* __restrict__ hnew,
                unsigned short* __restrict__ hnew_bf) {
    const int i = blockIdx.x * 256 + threadIdx.x;
    const int b = i >> 10, j = i & (HH - 1);
    const size_t o = (size_t)b * (3 * HH) + j;
    const float ir = gi[o], iz = gi[o + HH], in_ = gi[o + 2 * HH];
    const float hr = gh[o], hz = gh[o + HH], hn = gh[o + 2 * HH];
    const float r = 1.f / (1.f + __expf(-(ir + hr)));
    const float z = 1.f / (1.f + __expf(-(iz + hz)));
    const float n = tanhf(in_ + r * hn);
    const float v = (1.f - z) * n + z * h[i];
    hnew[i] = v;
    hnew_bf[i] = f2bf(v);
}

// ---------------------------------------------------------------------------
// In-place row log-softmax over V=32000, online (m,s) single read + write pass
// ---------------------------------------------------------------------------
__global__ __launch_bounds__(256)
void lsm_kernel(float* __restrict__ logits) {
    const int b = blockIdx.x, tid = threadIdx.x;
    float* row = logits + (size_t)b * VV;
    __shared__ float sm[4], ss[4];

    float m = -3.4e38f, s = 0.f;
    for (int j = tid; j < VV / 4; j += 256) {
        const float4 v = ((const float4*)row)[j];
        const float lm = fmaxf(fmaxf(v.x, v.y), fmaxf(v.z, v.w));
        const float nm = fmaxf(m, lm);
        s = s * __expf(m - nm) + __expf(v.x - nm) + __expf(v.y - nm)
            + __expf(v.z - nm) + __expf(v.w - nm);
        m = nm;
    }
    #pragma unroll
    for (int o = 32; o; o >>= 1) {
        const float mo = __shfl_xor(m, o), so = __shfl_xor(s, o);
        const float nm = fmaxf(m, mo);
        s = s * __expf(m - nm) + so * __expf(mo - nm);
        m = nm;
    }
    if ((tid & 63) == 0) { sm[tid >> 6] = m; ss[tid >> 6] = s; }
    __syncthreads();
    const float M = fmaxf(fmaxf(sm[0], sm[1]), fmaxf(sm[2], sm[3]));
    const float S = ss[0] * __expf(sm[0] - M) + ss[1] * __expf(sm[1] - M)
                  + ss[2] * __expf(sm[2] - M) + ss[3] * __expf(sm[3] - M);
    const float lse = M + __logf(S);
    for (int j = tid; j < VV / 4; j += 256) {
        float4 v = ((const float4*)row)[j];
        v.x -= lse; v.y -= lse; v.z -= lse; v.w -= lse;
        ((float4*)row)[j] = v;
    }
}

// ---------------------------------------------------------------------------
extern "C" void kernel_launch(void* const* d_in, const int* in_sizes, int n_in,
                              void* d_out, int out_size, void* d_ws, size_t ws_size,
                              hipStream_t stream) {
    const int*   ids       = (const int*)d_in[0];
    const float* hidden    = (const float*)d_in[1];
    const float* enc       = (const float*)d_in[2];
    const float* embedding = (const float*)d_in[4];
    const float* attn1_w   = (const float*)d_in[5];
    const float* attn1_b   = (const float*)d_in[6];
    const float* combine_w = (const float*)d_in[7];
    const float* combine_b = (const float*)d_in[8];
    const float* w_ih      = (const float*)d_in[9];
    const float* w_hh      = (const float*)d_in[10];
    const float* b_ih      = (const float*)d_in[11];
    const float* b_hh      = (const float*)d_in[12];
    const float* out_w     = (const float*)d_in[13];
    const float* out_b     = (const float*)d_in[14];

    float* out_lsm = (float*)d_out;                  // [B,V]
    float* out_h   = out_lsm + (size_t)BB * VV;      // [1,B,H]
    float* out_aw  = out_h + (size_t)BB * HH;        // [L,B,1]

    char* w = (char*)d_ws;
    unsigned short* out_w_bf = (unsigned short*)w;   w += (size_t)VV * HH * 2;
    unsigned short* w_ih_bf  = (unsigned short*)w;   w += (size_t)3 * HH * HH * 2;
    unsigned short* w_hh_bf  = (unsigned short*)w;   w += (size_t)3 * HH * HH * 2;
    unsigned short* w_cb_bf  = (unsigned short*)w;   w += (size_t)2 * HH * HH * 2;
    unsigned short* cat_bf   = (unsigned short*)w;   w += (size_t)BB * 2 * HH * 2;
    unsigned short* x_bf     = (unsigned short*)w;   w += (size_t)BB * HH * 2;
    unsigned short* hid_bf   = (unsigned short*)w;   w += (size_t)BB * HH * 2;
    unsigned short* hnew_bf  = (unsigned short*)w;   w += (size_t)BB * HH * 2;
    float* gi = (float*)w;                           w += (size_t)BB * 3 * HH * 4;
    float* gh = (float*)w;                           w += (size_t)BB * 3 * HH * 4;

    // weight/activation converts
    cvt_kernel<<<VV * HH / 8 / 256, 256, 0, stream>>>(out_w, out_w_bf, VV * HH / 8);
    cvt_kernel<<<3 * HH * HH / 8 / 256, 256, 0, stream>>>(w_ih, w_ih_bf, 3 * HH * HH / 8);
    cvt_kernel<<<3 * HH * HH / 8 / 256, 256, 0, stream>>>(w_hh, w_hh_bf, 3 * HH * HH / 8);
    cvt_kernel<<<2 * HH * HH / 8 / 256, 256, 0, stream>>>(combine_w, w_cb_bf, 2 * HH * HH / 8);
    cvt_kernel<<<BB * HH / 8 / 256, 256, 0, stream>>>(hidden, hid_bf, BB * HH / 8);

    attn_kernel<<<BB, 256, 0, stream>>>(ids, enc, embedding, attn1_w, attn1_b, out_aw, cat_bf);

    // x = relu(cat @ combine_w^T + b)   M=512 N=1024 K=2048  -> bf16
    gemm_nt<64, 64, 1, 0><<<dim3(HH / 64, BB / 64), 256, 0, stream>>>(
        (const bf16*)cat_bf, (const bf16*)w_cb_bf, combine_b, x_bf, 2 * HH, HH, 0);
    // gh = hidden @ w_hh^T + b_hh       M=512 N=3072 K=1024
    gemm_nt<64, 64, 0, 0><<<dim3(3 * HH / 64, BB / 64), 256, 0, stream>>>(
        (const bf16*)hid_bf, (const bf16*)w_hh_bf, b_hh, gh, HH, 3 * HH, 0);
    // gi = x @ w_ih^T + b_ih            M=512 N=3072 K=1024
    gemm_nt<64, 64, 0, 0><<<dim3(3 * HH / 64, BB / 64), 256, 0, stream>>>(
        (const bf16*)x_bf, (const bf16*)w_ih_bf, b_ih, gi, HH, 3 * HH, 0);

    gru_kernel<<<(BB * HH) / 256, 256, 0, stream>>>(gi, gh, hidden, out_h, hnew_bf);

    // logits = h_new @ out_w^T + out_b  M=512 N=32000 K=1024, XCD-swizzled 1D grid
    gemm_nt<128, 128, 0, 1><<<dim3((VV / 128) * 4), 256, 0, stream>>>(
        (const bf16*)hnew_bf, (const bf16*)out_w_bf, out_b, out_lsm, HH, VV, VV / 128);

    lsm_kernel<<<BB, 256, 0, stream>>>(out_lsm);
}

// Round 4
// 185.957 us; speedup vs baseline: 3.0627x; 1.2889x over previous
//
#include <hip/hip_runtime.h>

#define HH 1024
#define VV 32000
#define LL 15
#define BB 512

typedef __bf16 bf16;
typedef __bf16 bf16x4 __attribute__((ext_vector_type(4)));
typedef __bf16 bf16x8 __attribute__((ext_vector_type(8)));
typedef float f32x4 __attribute__((ext_vector_type(4)));

__device__ __forceinline__ unsigned short f2bf(float f) {
    unsigned int u = __float_as_uint(f);
    unsigned int r = (u + 0x7fffu + ((u >> 16) & 1u)) >> 16;  // RNE
    return (unsigned short)r;
}

__device__ __forceinline__ void gld_lds16(const void* g, void* l) {
    __builtin_amdgcn_global_load_lds(
        (const __attribute__((address_space(1))) unsigned int*)g,
        (__attribute__((address_space(3))) unsigned int*)l, 16, 0, 0);
}

// ---------------------------------------------------------------------------
// fused f32->bf16 convert over 4 segments (w_ih, w_hh, combine_w, hidden)
// ---------------------------------------------------------------------------
__global__ __launch_bounds__(256)
void cvt4_kernel(const float* __restrict__ a0, unsigned short* __restrict__ o0, int n0_,
                 const float* __restrict__ a1, unsigned short* __restrict__ o1, int n1_,
                 const float* __restrict__ a2, unsigned short* __restrict__ o2, int n2_,
                 const float* __restrict__ a3, unsigned short* __restrict__ o3, int n3_) {
    int i = blockIdx.x * 256 + threadIdx.x;  // float8 units
    const float* src; unsigned short* dst;
    if (i < n0_) { src = a0; dst = o0; }
    else if ((i -= n0_) < n1_) { src = a1; dst = o1; }
    else if ((i -= n1_) < n2_) { src = a2; dst = o2; }
    else if ((i -= n2_) < n3_) { src = a3; dst = o3; }
    else return;
    const f32x4 a = ((const f32x4*)src)[2 * i], b = ((const f32x4*)src)[2 * i + 1];
    ((bf16x4*)dst)[2 * i]     = __builtin_convertvector(a, bf16x4);
    ((bf16x4*)dst)[2 * i + 1] = __builtin_convertvector(b, bf16x4);
}

// ---------------------------------------------------------------------------
// Attention, single enc read: stage enc[.,b,:] (60 KB) in LDS.
// ---------------------------------------------------------------------------
__global__ __launch_bounds__(256)
void attn_kernel(const int* __restrict__ ids, const float* __restrict__ enc,
                 const float* __restrict__ embedding,
                 const float* __restrict__ attn1_w, const float* __restrict__ attn1_b,
                 float* __restrict__ attn_out, unsigned short* __restrict__ cat_out) {
    const int b = blockIdx.x, tid = threadIdx.x;
    const int lane = tid & 63, wv = tid >> 6;

    __shared__ float s_enc[LL * HH];
    __shared__ float s_scores[LL];
    __shared__ float s_red[4];

    // stage enc rows for this b
    for (int idx = tid; idx < LL * HH / 4; idx += 256) {
        const int l = (idx * 4) >> 10, h = (idx * 4) & (HH - 1);
        *(f32x4*)&s_enc[idx * 4] = *(const f32x4*)&enc[((size_t)l * BB + b) * HH + h];
    }

    const float* embr = embedding + (size_t)ids[b] * HH;
    float p = 0.f;
    for (int j = tid; j < HH; j += 256) p += embr[j] * attn1_w[j];
    #pragma unroll
    for (int o = 32; o; o >>= 1) p += __shfl_xor(p, o);
    if (lane == 0) s_red[wv] = p;
    __syncthreads();  // s_enc + s_red ready
    const float semb = s_red[0] + s_red[1] + s_red[2] + s_red[3] + attn1_b[0];

    for (int l = wv; l < LL; l += 4) {
        float q = 0.f;
        for (int j = lane; j < HH; j += 64) q += s_enc[l * HH + j] * attn1_w[HH + j];
        #pragma unroll
        for (int o = 32; o; o >>= 1) q += __shfl_xor(q, o);
        if (lane == 0) s_scores[l] = q + semb;
    }
    __syncthreads();

    float mx = -3.4e38f;
    #pragma unroll
    for (int l = 0; l < LL; l++) mx = fmaxf(mx, s_scores[l]);
    float aw[LL], sum = 0.f;
    #pragma unroll
    for (int l = 0; l < LL; l++) { aw[l] = __expf(s_scores[l] - mx); sum += aw[l]; }
    const float inv = 1.f / sum;
    #pragma unroll
    for (int l = 0; l < LL; l++) aw[l] *= inv;

    if (tid < LL) attn_out[tid * BB + b] = aw[tid];

    for (int j = tid; j < HH; j += 256) {
        float c = 0.f;
        #pragma unroll
        for (int l = 0; l < LL; l++) c += aw[l] * s_enc[l * HH + j];
        cat_out[(size_t)b * (2 * HH) + j] = f2bf(embr[j]);
        cat_out[(size_t)b * (2 * HH) + HH + j] = f2bf(c);
    }
}

// ---------------------------------------------------------------------------
// bf16 NT GEMM (m97 structure), small shapes. GATES=1: blockIdx.z picks
// the second operand set (gh / gi in one launch).
// ---------------------------------------------------------------------------
template<int TM, int TN, int OUT, int GATES>
__global__ __launch_bounds__(256)
void gemm_nt(const bf16* __restrict__ A, const bf16* __restrict__ B,
             const float* __restrict__ bias, void* __restrict__ Cout,
             const bf16* __restrict__ A2, const bf16* __restrict__ B2,
             const float* __restrict__ bias2, void* __restrict__ C2,
             const int K, const int N) {
    constexpr int FM = TM / 32, FN = TN / 32;
    __shared__ bf16 As[TM * 64];
    __shared__ bf16 Bs[TN * 64];

    if (GATES && blockIdx.z == 1) { A = A2; B = B2; bias = bias2; Cout = C2; }

    const int tid = threadIdx.x;
    const int lane = tid & 63, wave = tid >> 6;
    const int wm = wave >> 1, wn = wave & 1;
    const int rlo = lane & 15, khi = lane >> 4;
    const int m0 = blockIdx.y * TM, n0 = blockIdx.x * TN;

    f32x4 acc[FM][FN] = {};
    constexpr int IA = TM / 32, IB = TN / 32;

    for (int k0 = 0; k0 < K; k0 += 64) {
        #pragma unroll
        for (int i = 0; i < IA; i++) {
            const int t = (i * 256 + tid) * 8;
            gld_lds16(A + (size_t)(m0 + (t >> 6)) * K + (k0 + (t & 63)), As + i * 2048 + wave * 512);
        }
        #pragma unroll
        for (int i = 0; i < IB; i++) {
            const int t = (i * 256 + tid) * 8;
            gld_lds16(B + (size_t)(n0 + (t >> 6)) * K + (k0 + (t & 63)), Bs + i * 2048 + wave * 512);
        }
        __syncthreads();

        bf16x8 af[FM][2], bfr[FN][2];
        #pragma unroll
        for (int m = 0; m < FM; m++)
            #pragma unroll
            for (int ks = 0; ks < 2; ks++)
                af[m][ks] = *(const bf16x8*)(As + (wm * (TM / 2) + m * 16 + rlo) * 64 + ks * 32 + khi * 8);
        #pragma unroll
        for (int n = 0; n < FN; n++)
            #pragma unroll
            for (int ks = 0; ks < 2; ks++)
                bfr[n][ks] = *(const bf16x8*)(Bs + (wn * (TN / 2) + n * 16 + rlo) * 64 + ks * 32 + khi * 8);
        #pragma unroll
        for (int ks = 0; ks < 2; ks++)
            #pragma unroll
            for (int m = 0; m < FM; m++)
                #pragma unroll
                for (int n = 0; n < FN; n++)
                    acc[m][n] = __builtin_amdgcn_mfma_f32_16x16x32_bf16(af[m][ks], bfr[n][ks], acc[m][n], 0, 0, 0);
        __syncthreads();
    }

    #pragma unroll
    for (int m = 0; m < FM; m++) {
        const int gr = m0 + wm * (TM / 2) + m * 16 + khi * 4;
        #pragma unroll
        for (int n = 0; n < FN; n++) {
            const int gc = n0 + wn * (TN / 2) + n * 16 + rlo;
            const float bv = bias[gc];
            #pragma unroll
            for (int j = 0; j < 4; j++) {
                float v = acc[m][n][j] + bv;
                if (OUT == 1) {
                    v = fmaxf(v, 0.f);
                    ((unsigned short*)Cout)[(size_t)(gr + j) * N + gc] = f2bf(v);
                } else {
                    ((float*)Cout)[(size_t)(gr + j) * N + gc] = v;
                }
            }
        }
    }
}

// ---------------------------------------------------------------------------
// Logits GEMM: A bf16 [512,1024] via global_load_lds; B f32 [32000,1024]
// reg-staged -> bf16 -> XOR-swizzled LDS. Epilogue writes C (f32) + per-block
// per-row (max, sumexp) partials for log-softmax. XCD-bijective swizzled grid.
// ---------------------------------------------------------------------------
__global__ __launch_bounds__(256)
void gemm_out(const bf16* __restrict__ A, const float* __restrict__ B,
              const float* __restrict__ bias, float* __restrict__ C,
              float* __restrict__ pmax, float* __restrict__ psum) {
    constexpr int K = HH, N = VV;
    __shared__ bf16 As[128 * 64];
    __shared__ char BsB[128 * 128] __attribute__((aligned(128)));
    __shared__ float sPm[2][128], sPs[2][128];

    const int tid = threadIdx.x;
    const int lane = tid & 63, wave = tid >> 6;
    const int wm = wave >> 1, wn = wave & 1;
    const int rlo = lane & 15, khi = lane >> 4;

    // bijective XCD swizzle: 250 groups (n-blocks) x 4 m-blocks
    constexpr int gridN = VV / 128;             // 250
    constexpr int nFull = (gridN >> 3) << 5;    // 992
    const int bidx = blockIdx.x;
    int g, jm;
    if (bidx < nFull) { const int s = bidx >> 5, rem = bidx & 31; jm = rem >> 3; g = s * 8 + (rem & 7); }
    else { const int rem = bidx - nFull; constexpr int gleft = gridN & 7; g = (gridN & ~7) + rem % gleft; jm = rem / gleft; }
    const int n0 = g * 128, m0 = jm * 128;

    f32x4 acc[4][4] = {};

    for (int k0 = 0; k0 < K; k0 += 64) {
        // A tile 128x64 bf16 via async global->LDS
        #pragma unroll
        for (int i = 0; i < 4; i++) {
            const int t = (i * 256 + tid) * 8;
            gld_lds16(A + (size_t)(m0 + (t >> 6)) * K + (k0 + (t & 63)), As + i * 2048 + wave * 512);
        }
        // B tile 128x64 f32 -> bf16, swizzled LDS
        f32x4 bv[8];
        #pragma unroll
        for (int i = 0; i < 8; i++) {
            const int idx = i * 256 + tid;
            const int row = idx >> 4, c4 = idx & 15;
            bv[i] = *(const f32x4*)(B + (size_t)(n0 + row) * K + k0 + c4 * 4);
        }
        #pragma unroll
        for (int i = 0; i < 8; i++) {
            const int idx = i * 256 + tid;
            const int row = idx >> 4;
            bf16x4 w = __builtin_convertvector(bv[i], bf16x4);
            *(bf16x4*)(BsB + ((idx * 8) ^ ((row & 7) << 4))) = w;
        }
        __syncthreads();

        bf16x8 af[4][2], bfr[4][2];
        #pragma unroll
        for (int m = 0; m < 4; m++)
            #pragma unroll
            for (int ks = 0; ks < 2; ks++)
                af[m][ks] = *(const bf16x8*)(As + (wm * 64 + m * 16 + rlo) * 64 + ks * 32 + khi * 8);
        #pragma unroll
        for (int n = 0; n < 4; n++) {
            const int row = wn * 64 + n * 16 + rlo;
            #pragma unroll
            for (int ks = 0; ks < 2; ks++)
                bfr[n][ks] = *(const bf16x8*)(BsB + ((row * 128 + ks * 64 + khi * 16) ^ ((row & 7) << 4)));
        }
        #pragma unroll
        for (int ks = 0; ks < 2; ks++)
            #pragma unroll
            for (int m = 0; m < 4; m++)
                #pragma unroll
                for (int n = 0; n < 4; n++)
                    acc[m][n] = __builtin_amdgcn_mfma_f32_16x16x32_bf16(af[m][ks], bfr[n][ks], acc[m][n], 0, 0, 0);
        __syncthreads();
    }

    // epilogue: store C, accumulate per-row (max, sumexp) partials
    float bvn[4];
    #pragma unroll
    for (int n = 0; n < 4; n++) bvn[n] = bias[n0 + wn * 64 + n * 16 + rlo];

    #pragma unroll
    for (int m = 0; m < 4; m++) {
        const int rbase = wm * 64 + m * 16 + khi * 4;
        #pragma unroll
        for (int j = 0; j < 4; j++) {
            const int gr = m0 + rbase + j;
            float v[4];
            float lm = -3.4e38f;
            #pragma unroll
            for (int n = 0; n < 4; n++) {
                v[n] = acc[m][n][j] + bvn[n];
                C[(size_t)gr * N + n0 + wn * 64 + n * 16 + rlo] = v[n];
                lm = fmaxf(lm, v[n]);
            }
            #pragma unroll
            for (int o = 8; o; o >>= 1) lm = fmaxf(lm, __shfl_xor(lm, o));
            float ls = 0.f;
            #pragma unroll
            for (int n = 0; n < 4; n++) ls += __expf(v[n] - lm);
            #pragma unroll
            for (int o = 8; o; o >>= 1) ls += __shfl_xor(ls, o);
            if (rlo == 0) { sPm[wn][rbase + j] = lm; sPs[wn][rbase + j] = ls; }
        }
    }
    __syncthreads();
    if (tid < 128) {
        const float ma = sPm[0][tid], mb = sPm[1][tid];
        const float M = fmaxf(ma, mb);
        const float S = sPs[0][tid] * __expf(ma - M) + sPs[1][tid] * __expf(mb - M);
        pmax[(size_t)(m0 + tid) * 256 + g] = M;
        psum[(size_t)(m0 + tid) * 256 + g] = S;
    }
}

// ---------------------------------------------------------------------------
// GRU gates (x4 vectorized); writes h_new f32 (output) + bf16 (A operand)
// ---------------------------------------------------------------------------
__global__ __launch_bounds__(256)
void gru_kernel(const float* __restrict__ gi, const float* __restrict__ gh,
                const float* __restrict__ h, float* __restrict__ hnew,
                unsigned short* __restrict__ hnew_bf) {
    const int i = blockIdx.x * 256 + threadIdx.x;        // x4 elems
    const int e = i * 4;
    const int b = e >> 10, j = e & (HH - 1);
    const size_t o = ((size_t)b * 3 * HH + j) / 4;       // f32x4 units
    const f32x4 ir = ((const f32x4*)gi)[o],          iz = ((const f32x4*)gi)[o + HH / 4],
                in_ = ((const f32x4*)gi)[o + 2 * HH / 4];
    const f32x4 hr = ((const f32x4*)gh)[o],          hz = ((const f32x4*)gh)[o + HH / 4],
                hn = ((const f32x4*)gh)[o + 2 * HH / 4];
    const f32x4 hv = ((const f32x4*)h)[i];
    f32x4 out;
    ushort4 ob;
    #pragma unroll
    for (int c = 0; c < 4; c++) {
        const float r = 1.f / (1.f + __expf(-(ir[c] + hr[c])));
        const float z = 1.f / (1.f + __expf(-(iz[c] + hz[c])));
        const float n = tanhf(in_[c] + r * hn[c]);
        const float v = (1.f - z) * n + z * hv[c];
        out[c] = v;
        ((unsigned short*)&ob)[c] = f2bf(v);
    }
    ((f32x4*)hnew)[i] = out;
    ((ushort4*)hnew_bf)[i] = ob;
}

// ---------------------------------------------------------------------------
// log-softmax finalize: combine 250 per-block partials -> lse, subtract.
// ---------------------------------------------------------------------------
__global__ __launch_bounds__(256)
void lsm_final(const float* __restrict__ pmax, const float* __restrict__ psum,
               float* __restrict__ logits) {
    const int b = blockIdx.x, tid = threadIdx.x;
    const int lane = tid & 63, wv = tid >> 6;
    __shared__ float sm[4], ss[4];

    float m = -3.4e38f, s = 0.f;
    if (tid < VV / 128) { m = pmax[(size_t)b * 256 + tid]; s = psum[(size_t)b * 256 + tid]; }
    #pragma unroll
    for (int o = 32; o; o >>= 1) {
        const float mo = __shfl_xor(m, o), so = __shfl_xor(s, o);
        const float nm = fmaxf(m, mo);
        s = s * __expf(m - nm) + so * __expf(mo - nm);
        m = nm;
    }
    if (lane == 0) { sm[wv] = m; ss[wv] = s; }
    __syncthreads();
    const float M = fmaxf(fmaxf(sm[0], sm[1]), fmaxf(sm[2], sm[3]));
    const float S = ss[0] * __expf(sm[0] - M) + ss[1] * __expf(sm[1] - M)
                  + ss[2] * __expf(sm[2] - M) + ss[3] * __expf(sm[3] - M);
    const float lse = M + __logf(S);

    float* row = logits + (size_t)b * VV;
    for (int j = tid; j < VV / 4; j += 256) {
        f32x4 v = ((const f32x4*)row)[j];
        v[0] -= lse; v[1] -= lse; v[2] -= lse; v[3] -= lse;
        ((f32x4*)row)[j] = v;
    }
}

// ---------------------------------------------------------------------------
extern "C" void kernel_launch(void* const* d_in, const int* in_sizes, int n_in,
                              void* d_out, int out_size, void* d_ws, size_t ws_size,
                              hipStream_t stream) {
    const int*   ids       = (const int*)d_in[0];
    const float* hidden    = (const float*)d_in[1];
    const float* enc       = (const float*)d_in[2];
    const float* embedding = (const float*)d_in[4];
    const float* attn1_w   = (const float*)d_in[5];
    const float* attn1_b   = (const float*)d_in[6];
    const float* combine_w = (const float*)d_in[7];
    const float* combine_b = (const float*)d_in[8];
    const float* w_ih      = (const float*)d_in[9];
    const float* w_hh      = (const float*)d_in[10];
    const float* b_ih      = (const float*)d_in[11];
    const float* b_hh      = (const float*)d_in[12];
    const float* out_w     = (const float*)d_in[13];
    const float* out_b     = (const float*)d_in[14];

    float* out_lsm = (float*)d_out;                  // [B,V]
    float* out_h   = out_lsm + (size_t)BB * VV;      // [1,B,H]
    float* out_aw  = out_h + (size_t)BB * HH;        // [L,B,1]

    char* w = (char*)d_ws;
    unsigned short* w_ih_bf  = (unsigned short*)w;   w += (size_t)3 * HH * HH * 2;
    unsigned short* w_hh_bf  = (unsigned short*)w;   w += (size_t)3 * HH * HH * 2;
    unsigned short* w_cb_bf  = (unsigned short*)w;   w += (size_t)2 * HH * HH * 2;
    unsigned short* cat_bf   = (unsigned short*)w;   w += (size_t)BB * 2 * HH * 2;
    unsigned short* x_bf     = (unsigned short*)w;   w += (size_t)BB * HH * 2;
    unsigned short* hid_bf   = (unsigned short*)w;   w += (size_t)BB * HH * 2;
    unsigned short* hnew_bf  = (unsigned short*)w;   w += (size_t)BB * HH * 2;
    float* gi   = (float*)w;                         w += (size_t)BB * 3 * HH * 4;
    float* gh   = (float*)w;                         w += (size_t)BB * 3 * HH * 4;
    float* pmax = (float*)w;                         w += (size_t)BB * 256 * 4;
    float* psum = (float*)w;                         w += (size_t)BB * 256 * 4;

    // one fused convert: w_ih, w_hh, combine_w, hidden
    cvt4_kernel<<<(3 * HH * HH / 8 * 2 + 2 * HH * HH / 8 + BB * HH / 8) / 256, 256, 0, stream>>>(
        w_ih, w_ih_bf, 3 * HH * HH / 8,
        w_hh, w_hh_bf, 3 * HH * HH / 8,
        combine_w, w_cb_bf, 2 * HH * HH / 8,
        hidden, hid_bf, BB * HH / 8);

    attn_kernel<<<BB, 256, 0, stream>>>(ids, enc, embedding, attn1_w, attn1_b, out_aw, cat_bf);

    // x = relu(cat @ combine_w^T + b)   M=512 N=1024 K=2048 -> bf16
    gemm_nt<64, 64, 1, 0><<<dim3(HH / 64, BB / 64), 256, 0, stream>>>(
        (const bf16*)cat_bf, (const bf16*)w_cb_bf, combine_b, x_bf,
        nullptr, nullptr, nullptr, nullptr, 2 * HH, HH);

    // z=0: gh = hidden @ w_hh^T ; z=1: gi = x @ w_ih^T   M=512 N=3072 K=1024
    gemm_nt<64, 64, 0, 1><<<dim3(3 * HH / 64, BB / 64, 2), 256, 0, stream>>>(
        (const bf16*)hid_bf, (const bf16*)w_hh_bf, b_hh, gh,
        (const bf16*)x_bf, (const bf16*)w_ih_bf, b_ih, gi, HH, 3 * HH);

    gru_kernel<<<(BB * HH / 4) / 256, 256, 0, stream>>>(gi, gh, hidden, out_h, hnew_bf);

    // logits + lsm partials   M=512 N=32000 K=1024
    gemm_out<<<(VV / 128) * 4, 256, 0, stream>>>(
        (const bf16*)hnew_bf, out_w, out_b, out_lsm, pmax, psum);

    lsm_final<<<BB, 256, 0, stream>>>(pmax, psum, out_lsm);
}

// Round 5
// 183.012 us; speedup vs baseline: 3.1119x; 1.0161x over previous
//
#include <hip/hip_runtime.h>

#define HH 1024
#define VV 32000
#define LL 15
#define BB 512

typedef __bf16 bf16;
typedef __bf16 bf16x4 __attribute__((ext_vector_type(4)));
typedef __bf16 bf16x8 __attribute__((ext_vector_type(8)));
typedef float f32x4 __attribute__((ext_vector_type(4)));

__device__ __forceinline__ unsigned short f2bf(float f) {
    unsigned int u = __float_as_uint(f);
    unsigned int r = (u + 0x7fffu + ((u >> 16) & 1u)) >> 16;  // RNE
    return (unsigned short)r;
}

__device__ __forceinline__ void gld_lds16(const void* g, void* l) {
    __builtin_amdgcn_global_load_lds(
        (const __attribute__((address_space(1))) unsigned int*)g,
        (__attribute__((address_space(3))) unsigned int*)l, 16, 0, 0);
}

// ---------------------------------------------------------------------------
// fused f32->bf16 convert over 4 segments (w_ih, w_hh, combine_w, hidden)
// ---------------------------------------------------------------------------
__global__ __launch_bounds__(256)
void cvt4_kernel(const float* __restrict__ a0, unsigned short* __restrict__ o0, int n0_,
                 const float* __restrict__ a1, unsigned short* __restrict__ o1, int n1_,
                 const float* __restrict__ a2, unsigned short* __restrict__ o2, int n2_,
                 const float* __restrict__ a3, unsigned short* __restrict__ o3, int n3_) {
    int i = blockIdx.x * 256 + threadIdx.x;  // float8 units
    const float* src; unsigned short* dst;
    if (i < n0_) { src = a0; dst = o0; }
    else if ((i -= n0_) < n1_) { src = a1; dst = o1; }
    else if ((i -= n1_) < n2_) { src = a2; dst = o2; }
    else if ((i -= n2_) < n3_) { src = a3; dst = o3; }
    else return;
    const f32x4 a = ((const f32x4*)src)[2 * i], b = ((const f32x4*)src)[2 * i + 1];
    ((bf16x4*)dst)[2 * i]     = __builtin_convertvector(a, bf16x4);
    ((bf16x4*)dst)[2 * i + 1] = __builtin_convertvector(b, bf16x4);
}

// ---------------------------------------------------------------------------
// Attention, single enc read: stage enc[.,b,:] (60 KB) in LDS.
// ---------------------------------------------------------------------------
__global__ __launch_bounds__(256)
void attn_kernel(const int* __restrict__ ids, const float* __restrict__ enc,
                 const float* __restrict__ embedding,
                 const float* __restrict__ attn1_w, const float* __restrict__ attn1_b,
                 float* __restrict__ attn_out, unsigned short* __restrict__ cat_out) {
    const int b = blockIdx.x, tid = threadIdx.x;
    const int lane = tid & 63, wv = tid >> 6;

    __shared__ float s_enc[LL * HH];
    __shared__ float s_scores[LL];
    __shared__ float s_red[4];

    for (int idx = tid; idx < LL * HH / 4; idx += 256) {
        const int l = (idx * 4) >> 10, h = (idx * 4) & (HH - 1);
        *(f32x4*)&s_enc[idx * 4] = *(const f32x4*)&enc[((size_t)l * BB + b) * HH + h];
    }

    const float* embr = embedding + (size_t)ids[b] * HH;
    float p = 0.f;
    for (int j = tid; j < HH; j += 256) p += embr[j] * attn1_w[j];
    #pragma unroll
    for (int o = 32; o; o >>= 1) p += __shfl_xor(p, o);
    if (lane == 0) s_red[wv] = p;
    __syncthreads();  // s_enc + s_red ready
    const float semb = s_red[0] + s_red[1] + s_red[2] + s_red[3] + attn1_b[0];

    for (int l = wv; l < LL; l += 4) {
        float q = 0.f;
        for (int j = lane; j < HH; j += 64) q += s_enc[l * HH + j] * attn1_w[HH + j];
        #pragma unroll
        for (int o = 32; o; o >>= 1) q += __shfl_xor(q, o);
        if (lane == 0) s_scores[l] = q + semb;
    }
    __syncthreads();

    float mx = -3.4e38f;
    #pragma unroll
    for (int l = 0; l < LL; l++) mx = fmaxf(mx, s_scores[l]);
    float aw[LL], sum = 0.f;
    #pragma unroll
    for (int l = 0; l < LL; l++) { aw[l] = __expf(s_scores[l] - mx); sum += aw[l]; }
    const float inv = 1.f / sum;
    #pragma unroll
    for (int l = 0; l < LL; l++) aw[l] *= inv;

    if (tid < LL) attn_out[tid * BB + b] = aw[tid];

    for (int j = tid; j < HH; j += 256) {
        float c = 0.f;
        #pragma unroll
        for (int l = 0; l < LL; l++) c += aw[l] * s_enc[l * HH + j];
        cat_out[(size_t)b * (2 * HH) + j] = f2bf(embr[j]);
        cat_out[(size_t)b * (2 * HH) + HH + j] = f2bf(c);
    }
}

// ---------------------------------------------------------------------------
// bf16 NT GEMM (m97 structure), small shapes. GATES=1: blockIdx.z picks
// the second operand set (gh / gi in one launch).
// ---------------------------------------------------------------------------
template<int TM, int TN, int OUT, int GATES>
__global__ __launch_bounds__(256)
void gemm_nt(const bf16* __restrict__ A, const bf16* __restrict__ B,
             const float* __restrict__ bias, void* __restrict__ Cout,
             const bf16* __restrict__ A2, const bf16* __restrict__ B2,
             const float* __restrict__ bias2, void* __restrict__ C2,
             const int K, const int N) {
    constexpr int FM = TM / 32, FN = TN / 32;
    __shared__ bf16 As[TM * 64];
    __shared__ bf16 Bs[TN * 64];

    if (GATES && blockIdx.z == 1) { A = A2; B = B2; bias = bias2; Cout = C2; }

    const int tid = threadIdx.x;
    const int lane = tid & 63, wave = tid >> 6;
    const int wm = wave >> 1, wn = wave & 1;
    const int rlo = lane & 15, khi = lane >> 4;
    const int m0 = blockIdx.y * TM, n0 = blockIdx.x * TN;

    f32x4 acc[FM][FN] = {};
    constexpr int IA = TM / 32, IB = TN / 32;

    for (int k0 = 0; k0 < K; k0 += 64) {
        #pragma unroll
        for (int i = 0; i < IA; i++) {
            const int t = (i * 256 + tid) * 8;
            gld_lds16(A + (size_t)(m0 + (t >> 6)) * K + (k0 + (t & 63)), As + i * 2048 + wave * 512);
        }
        #pragma unroll
        for (int i = 0; i < IB; i++) {
            const int t = (i * 256 + tid) * 8;
            gld_lds16(B + (size_t)(n0 + (t >> 6)) * K + (k0 + (t & 63)), Bs + i * 2048 + wave * 512);
        }
        __syncthreads();

        bf16x8 af[FM][2], bfr[FN][2];
        #pragma unroll
        for (int m = 0; m < FM; m++)
            #pragma unroll
            for (int ks = 0; ks < 2; ks++)
                af[m][ks] = *(const bf16x8*)(As + (wm * (TM / 2) + m * 16 + rlo) * 64 + ks * 32 + khi * 8);
        #pragma unroll
        for (int n = 0; n < FN; n++)
            #pragma unroll
            for (int ks = 0; ks < 2; ks++)
                bfr[n][ks] = *(const bf16x8*)(Bs + (wn * (TN / 2) + n * 16 + rlo) * 64 + ks * 32 + khi * 8);
        #pragma unroll
        for (int ks = 0; ks < 2; ks++)
            #pragma unroll
            for (int m = 0; m < FM; m++)
                #pragma unroll
                for (int n = 0; n < FN; n++)
                    acc[m][n] = __builtin_amdgcn_mfma_f32_16x16x32_bf16(af[m][ks], bfr[n][ks], acc[m][n], 0, 0, 0);
        __syncthreads();
    }

    #pragma unroll
    for (int m = 0; m < FM; m++) {
        const int gr = m0 + wm * (TM / 2) + m * 16 + khi * 4;
        #pragma unroll
        for (int n = 0; n < FN; n++) {
            const int gc = n0 + wn * (TN / 2) + n * 16 + rlo;
            const float bv = bias[gc];
            #pragma unroll
            for (int j = 0; j < 4; j++) {
                float v = acc[m][n][j] + bv;
                if (OUT == 1) {
                    v = fmaxf(v, 0.f);
                    ((unsigned short*)Cout)[(size_t)(gr + j) * N + gc] = f2bf(v);
                } else {
                    ((float*)Cout)[(size_t)(gr + j) * N + gc] = v;
                }
            }
        }
    }
}

// ---------------------------------------------------------------------------
// Logits GEMM: TM=128 x TN=64, 2000 blocks. A bf16 via global_load_lds with
// PRE-SWIZZLED source (LDS dest stays linear); B f32 reg-staged -> bf16 ->
// XOR-swizzled ds_write. Frag reads apply the same involution -> 2-way free.
// Epilogue: C f32 + per-block per-row (max,sumexp) partials.
// ---------------------------------------------------------------------------
__global__ __launch_bounds__(256, 3)
void gemm_out(const bf16* __restrict__ A, const float* __restrict__ B,
              const float* __restrict__ bias, float* __restrict__ C,
              float* __restrict__ pmax, float* __restrict__ psum) {
    constexpr int K = HH, N = VV;
    __shared__ bf16 As[128 * 64];     // swizzled content, linear dest
    __shared__ bf16 Bs[64 * 64];      // swizzled content
    __shared__ float sPm[2][128], sPs[2][128];

    const int tid = threadIdx.x;
    const int lane = tid & 63, wave = tid >> 6;
    const int wm = wave >> 1, wn = wave & 1;
    const int rlo = lane & 15, khi = lane >> 4;

    // XCD swizzle: 500 n-panels x 4 m-blocks; chunk of 32 = 4 jm x 8 g so a
    // panel's 4 m-blocks land on one XCD.
    constexpr int gridN = VV / 64;              // 500
    constexpr int nFull = (gridN >> 3) << 5;    // 1984
    const int bidx = blockIdx.x;
    int g, jm;
    if (bidx < nFull) { const int s = bidx >> 5, rem = bidx & 31; jm = rem >> 3; g = s * 8 + (rem & 7); }
    else { const int rem = bidx - nFull; constexpr int gleft = gridN & 7; g = (gridN & ~7) + rem % gleft; jm = rem / gleft; }
    const int n0 = g * 64, m0 = jm * 128;

    f32x4 acc[4][2] = {};

    for (int k0 = 0; k0 < K; k0 += 64) {
        // B tile 64x64 f32: 1024 f32x4 slots, 4 per thread (issue loads first)
        f32x4 bv[4];
        #pragma unroll
        for (int i = 0; i < 4; i++) {
            const int idx = i * 256 + tid;
            const int row = idx >> 4, c4 = idx & 15;
            bv[i] = *(const f32x4*)(B + (size_t)(n0 + row) * K + k0 + c4 * 4);
        }
        // A tile 128x64 bf16, pre-swizzled global source, linear LDS dest
        #pragma unroll
        for (int i = 0; i < 4; i++) {
            const int p = (i * 256 + tid) * 16;          // byte pos in As
            const int row = p >> 7;
            const int qs = (p & 127) ^ ((row & 7) << 4); // swizzled src col bytes
            gld_lds16(A + (size_t)(m0 + row) * K + k0 + (qs >> 1),
                      As + i * 2048 + wave * 512);
        }
        // B cvt + swizzled write
        #pragma unroll
        for (int i = 0; i < 4; i++) {
            const int idx = i * 256 + tid;
            const int row = idx >> 4, c4 = idx & 15;
            bf16x4 w = __builtin_convertvector(bv[i], bf16x4);
            *(bf16x4*)((char*)Bs + row * 128 + ((c4 * 8) ^ ((row & 7) << 4))) = w;
        }
        __syncthreads();

        #pragma unroll
        for (int ks = 0; ks < 2; ks++) {
            bf16x8 af[4], bfr[2];
            #pragma unroll
            for (int m = 0; m < 4; m++) {
                const int r = wm * 64 + m * 16 + rlo;
                const int sw = (ks * 64 + khi * 16) ^ ((r & 7) << 4);
                af[m] = *(const bf16x8*)((const char*)As + r * 128 + sw);
            }
            #pragma unroll
            for (int n = 0; n < 2; n++) {
                const int r = wn * 32 + n * 16 + rlo;
                const int sw = (ks * 64 + khi * 16) ^ ((r & 7) << 4);
                bfr[n] = *(const bf16x8*)((const char*)Bs + r * 128 + sw);
            }
            #pragma unroll
            for (int m = 0; m < 4; m++)
                #pragma unroll
                for (int n = 0; n < 2; n++)
                    acc[m][n] = __builtin_amdgcn_mfma_f32_16x16x32_bf16(af[m], bfr[n], acc[m][n], 0, 0, 0);
        }
        __syncthreads();
    }

    // epilogue: store C, per-row (max,sumexp) partials over this 64-col block
    float bvn[2];
    #pragma unroll
    for (int n = 0; n < 2; n++) bvn[n] = bias[n0 + wn * 32 + n * 16 + rlo];

    #pragma unroll
    for (int m = 0; m < 4; m++) {
        const int rbase = wm * 64 + m * 16 + khi * 4;
        #pragma unroll
        for (int j = 0; j < 4; j++) {
            const int gr = m0 + rbase + j;
            float v[2];
            #pragma unroll
            for (int n = 0; n < 2; n++) {
                v[n] = acc[m][n][j] + bvn[n];
                C[(size_t)gr * N + n0 + wn * 32 + n * 16 + rlo] = v[n];
            }
            float lm = fmaxf(v[0], v[1]);
            #pragma unroll
            for (int o = 8; o; o >>= 1) lm = fmaxf(lm, __shfl_xor(lm, o));
            float ls = __expf(v[0] - lm) + __expf(v[1] - lm);
            #pragma unroll
            for (int o = 8; o; o >>= 1) ls += __shfl_xor(ls, o);
            if (rlo == 0) { sPm[wn][rbase + j] = lm; sPs[wn][rbase + j] = ls; }
        }
    }
    __syncthreads();
    if (tid < 128) {
        const float ma = sPm[0][tid], mb = sPm[1][tid];
        const float M = fmaxf(ma, mb);
        const float S = sPs[0][tid] * __expf(ma - M) + sPs[1][tid] * __expf(mb - M);
        pmax[(size_t)(m0 + tid) * 512 + g] = M;
        psum[(size_t)(m0 + tid) * 512 + g] = S;
    }
}

// ---------------------------------------------------------------------------
// GRU gates (x4 vectorized); writes h_new f32 (output) + bf16 (A operand)
// ---------------------------------------------------------------------------
__global__ __launch_bounds__(256)
void gru_kernel(const float* __restrict__ gi, const float* __restrict__ gh,
                const float* __restrict__ h, float* __restrict__ hnew,
                unsigned short* __restrict__ hnew_bf) {
    const int i = blockIdx.x * 256 + threadIdx.x;        // x4 elems
    const int e = i * 4;
    const int b = e >> 10, j = e & (HH - 1);
    const size_t o = ((size_t)b * 3 * HH + j) / 4;       // f32x4 units
    const f32x4 ir = ((const f32x4*)gi)[o],          iz = ((const f32x4*)gi)[o + HH / 4],
                in_ = ((const f32x4*)gi)[o + 2 * HH / 4];
    const f32x4 hr = ((const f32x4*)gh)[o],          hz = ((const f32x4*)gh)[o + HH / 4],
                hn = ((const f32x4*)gh)[o + 2 * HH / 4];
    const f32x4 hv = ((const f32x4*)h)[i];
    f32x4 out;
    ushort4 ob;
    #pragma unroll
    for (int c = 0; c < 4; c++) {
        const float r = 1.f / (1.f + __expf(-(ir[c] + hr[c])));
        const float z = 1.f / (1.f + __expf(-(iz[c] + hz[c])));
        const float n = tanhf(in_[c] + r * hn[c]);
        const float v = (1.f - z) * n + z * hv[c];
        out[c] = v;
        ((unsigned short*)&ob)[c] = f2bf(v);
    }
    ((f32x4*)hnew)[i] = out;
    ((ushort4*)hnew_bf)[i] = ob;
}

// ---------------------------------------------------------------------------
// log-softmax finalize: combine 500 per-block partials -> lse, subtract.
// ---------------------------------------------------------------------------
__global__ __launch_bounds__(512)
void lsm_final(const float* __restrict__ pmax, const float* __restrict__ psum,
               float* __restrict__ logits) {
    const int b = blockIdx.x, tid = threadIdx.x;
    const int lane = tid & 63, wv = tid >> 6;
    __shared__ float sm[8], ss[8];

    float m = -3.4e38f, s = 0.f;
    if (tid < VV / 64) { m = pmax[(size_t)b * 512 + tid]; s = psum[(size_t)b * 512 + tid]; }
    #pragma unroll
    for (int o = 32; o; o >>= 1) {
        const float mo = __shfl_xor(m, o), so = __shfl_xor(s, o);
        const float nm = fmaxf(m, mo);
        s = s * __expf(m - nm) + so * __expf(mo - nm);
        m = nm;
    }
    if (lane == 0) { sm[wv] = m; ss[wv] = s; }
    __syncthreads();
    float M = sm[0], S;
    #pragma unroll
    for (int w = 1; w < 8; w++) M = fmaxf(M, sm[w]);
    S = ss[0] * __expf(sm[0] - M);
    #pragma unroll
    for (int w = 1; w < 8; w++) S += ss[w] * __expf(sm[w] - M);
    const float lse = M + __logf(S);

    float* row = logits + (size_t)b * VV;
    for (int j = tid; j < VV / 4; j += 512) {
        f32x4 v = ((const f32x4*)row)[j];
        v[0] -= lse; v[1] -= lse; v[2] -= lse; v[3] -= lse;
        ((f32x4*)row)[j] = v;
    }
}

// ---------------------------------------------------------------------------
extern "C" void kernel_launch(void* const* d_in, const int* in_sizes, int n_in,
                              void* d_out, int out_size, void* d_ws, size_t ws_size,
                              hipStream_t stream) {
    const int*   ids       = (const int*)d_in[0];
    const float* hidden    = (const float*)d_in[1];
    const float* enc       = (const float*)d_in[2];
    const float* embedding = (const float*)d_in[4];
    const float* attn1_w   = (const float*)d_in[5];
    const float* attn1_b   = (const float*)d_in[6];
    const float* combine_w = (const float*)d_in[7];
    const float* combine_b = (const float*)d_in[8];
    const float* w_ih      = (const float*)d_in[9];
    const float* w_hh      = (const float*)d_in[10];
    const float* b_ih      = (const float*)d_in[11];
    const float* b_hh      = (const float*)d_in[12];
    const float* out_w     = (const float*)d_in[13];
    const float* out_b     = (const float*)d_in[14];

    float* out_lsm = (float*)d_out;                  // [B,V]
    float* out_h   = out_lsm + (size_t)BB * VV;      // [1,B,H]
    float* out_aw  = out_h + (size_t)BB * HH;        // [L,B,1]

    char* w = (char*)d_ws;
    unsigned short* w_ih_bf  = (unsigned short*)w;   w += (size_t)3 * HH * HH * 2;
    unsigned short* w_hh_bf  = (unsigned short*)w;   w += (size_t)3 * HH * HH * 2;
    unsigned short* w_cb_bf  = (unsigned short*)w;   w += (size_t)2 * HH * HH * 2;
    unsigned short* cat_bf   = (unsigned short*)w;   w += (size_t)BB * 2 * HH * 2;
    unsigned short* x_bf     = (unsigned short*)w;   w += (size_t)BB * HH * 2;
    unsigned short* hid_bf   = (unsigned short*)w;   w += (size_t)BB * HH * 2;
    unsigned short* hnew_bf  = (unsigned short*)w;   w += (size_t)BB * HH * 2;
    float* gi   = (float*)w;                         w += (size_t)BB * 3 * HH * 4;
    float* gh   = (float*)w;                         w += (size_t)BB * 3 * HH * 4;
    float* pmax = (float*)w;                         w += (size_t)BB * 512 * 4;
    float* psum = (float*)w;                         w += (size_t)BB * 512 * 4;

    cvt4_kernel<<<(3 * HH * HH / 8 * 2 + 2 * HH * HH / 8 + BB * HH / 8) / 256, 256, 0, stream>>>(
        w_ih, w_ih_bf, 3 * HH * HH / 8,
        w_hh, w_hh_bf, 3 * HH * HH / 8,
        combine_w, w_cb_bf, 2 * HH * HH / 8,
        hidden, hid_bf, BB * HH / 8);

    attn_kernel<<<BB, 256, 0, stream>>>(ids, enc, embedding, attn1_w, attn1_b, out_aw, cat_bf);

    // x = relu(cat @ combine_w^T + b)   M=512 N=1024 K=2048 -> bf16
    gemm_nt<64, 64, 1, 0><<<dim3(HH / 64, BB / 64), 256, 0, stream>>>(
        (const bf16*)cat_bf, (const bf16*)w_cb_bf, combine_b, x_bf,
        nullptr, nullptr, nullptr, nullptr, 2 * HH, HH);

    // z=0: gh = hidden @ w_hh^T ; z=1: gi = x @ w_ih^T   M=512 N=3072 K=1024
    gemm_nt<64, 64, 0, 1><<<dim3(3 * HH / 64, BB / 64, 2), 256, 0, stream>>>(
        (const bf16*)hid_bf, (const bf16*)w_hh_bf, b_hh, gh,
        (const bf16*)x_bf, (const bf16*)w_ih_bf, b_ih, gi, HH, 3 * HH);

    gru_kernel<<<(BB * HH / 4) / 256, 256, 0, stream>>>(gi, gh, hidden, out_h, hnew_bf);

    // logits + lsm partials   M=512 N=32000 K=1024
    gemm_out<<<(VV / 64) * 4, 256, 0, stream>>>(
        (const bf16*)hnew_bf, out_w, out_b, out_lsm, pmax, psum);

    lsm_final<<<BB, 512, 0, stream>>>(pmax, psum, out_lsm);
}